// Round 7
// baseline (2450.175 us; speedup 1.0000x reference)
//
#include <hip/hip_runtime.h>
#include <math.h>

#define KCB 65536
#define DIM 32
#define NQ  32768            // B*T = 8*4096
#define KSPLIT 8
#define CPS (KCB / KSPLIT)   // 8192 codes per split
#define STAGE_C 128          // codes staged in LDS per step
#define NSTAGE (CPS / STAGE_C) // 64
#define QB  512              // queries per block
#define NQB (NQ / QB)        // 64 query blocks
#define ROWB 144             // LDS bytes per code row: 64 hi + 64 lo + 16 pad
#define ROWS (ROWB/2)        // 72 shorts
#define NZQ (NQ * DIM)       // 1048576 z_q elements
#define MARGIN 1e-3f

// ---- workspace layout (units of 4 bytes) ----
#define OFF_CB      ((size_t)0)                       // K*D floats (projected codebook)
#define OFF_CBN     (OFF_CB + (size_t)KCB * DIM)      // K floats (||cb||^2)
#define OFF_PD1     (OFF_CBN + KCB)                   // NQ*KSPLIT floats
#define OFF_PD2     (OFF_PD1 + (size_t)NQ * KSPLIT)   // NQ*KSPLIT floats
#define OFF_PI1     (OFF_PD2 + (size_t)NQ * KSPLIT)   // NQ*KSPLIT ints
#define OFF_FIDX    (OFF_PI1 + (size_t)NQ * KSPLIT)   // NQ ints
#define OFF_LIST    (OFF_FIDX + NQ)                   // NQ ints
#define OFF_COUNTS  (OFF_LIST + NQ)                   // K floats
#define OFF_CNT     (OFF_COUNTS + KCB)                // 1 int
#define OFF_STATS   (OFF_CNT + 1)                     // 2 floats (S, U)

typedef __attribute__((ext_vector_type(8))) short bf16x8;
typedef __attribute__((ext_vector_type(4))) short s16x4;
typedef __attribute__((ext_vector_type(4))) float f32x4;

__device__ __forceinline__ unsigned short f2bf(float f) {
    unsigned int u = __builtin_bit_cast(unsigned int, f);
    unsigned int r = (u + 0x7FFFu + ((u >> 16) & 1u)) >> 16;  // RNE
    return (unsigned short)r;
}
__device__ __forceinline__ float bf2f(unsigned short h) {
    unsigned int u = ((unsigned int)h) << 16;
    return __builtin_bit_cast(float, u);
}

__global__ __launch_bounds__(256) void zero_kernel(float* __restrict__ p, int n) {
    int i = blockIdx.x * 256 + threadIdx.x;
    if (i < n) p[i] = 0.0f;
}

// cb = codebook @ W + bias  (double accumulate -> round), plus exact row norms
__global__ __launch_bounds__(256) void project_kernel(
    const float* __restrict__ codebook, const float* __restrict__ W,
    const float* __restrict__ bias, float* __restrict__ cb, float* __restrict__ cbn)
{
    __shared__ float Ws[DIM * DIM];
    __shared__ float bs[DIM];
    int tid = threadIdx.x;
#pragma unroll
    for (int r = 0; r < 4; ++r) Ws[tid + 256 * r] = W[tid + 256 * r];
    if (tid < DIM) bs[tid] = bias[tid];
    __syncthreads();
    int k = blockIdx.x * 256 + tid;
    float row[DIM];
    const float4* src = (const float4*)(codebook + (size_t)k * DIM);
#pragma unroll
    for (int c = 0; c < 8; ++c) {
        float4 v = src[c];
        row[4*c] = v.x; row[4*c+1] = v.y; row[4*c+2] = v.z; row[4*c+3] = v.w;
    }
    float out[DIM];
    double nrm = 0.0;
#pragma unroll
    for (int d = 0; d < DIM; ++d) {
        double acc = 0.0;
#pragma unroll
        for (int j = 0; j < DIM; ++j) acc += (double)row[j] * (double)Ws[j * DIM + d];
        acc += (double)bs[d];
        float o = (float)acc;
        out[d] = o;
        nrm += (double)o * (double)o;
    }
    float4* dst = (float4*)(cb + (size_t)k * DIM);
#pragma unroll
    for (int c = 0; c < 8; ++c)
        dst[c] = make_float4(out[4*c], out[4*c+1], out[4*c+2], out[4*c+3]);
    cbn[k] = (float)nrm;
}

// MFMA-based top-2 NN search on partial distance p = ||c||^2 - 2 z.c
// (zn omitted: constant per query, cancels in argmin and in d2-d1 margin).
// Block: 1024 thr = 16 waves = 8 q-groups x 2 c-groups; 512 queries/block.
// Grid: (NQ/512, KSPLIT). A = bf16 hi/lo of (-2z) resident in regs;
// codes converted fp32->bf16 hi/lo while staging into LDS (dbuf).
// __launch_bounds__(1024, 4): 4 waves/EU -> 128-VGPR cap. R5 at the default
// (8 waves/EU, 64 VGPR) spilled ~45 regs -> 7.3 GB scratch traffic/dispatch.
__global__ __launch_bounds__(1024, 4) void search_kernel(
    const float* __restrict__ z, const float* __restrict__ cb,
    const float* __restrict__ cbn,
    float* __restrict__ pd1, float* __restrict__ pd2, int* __restrict__ pi1)
{
    __shared__ __align__(16) unsigned char smem[2*STAGE_C*ROWB + 2*STAGE_C*4];
    // reduction arrays alias stage buffers (used only after final barrier)
    float* redD1 = (float*)smem;
    float* redD2 = (float*)(smem + 4096);
    int*   redI1 = (int*)(smem + 8192);

    const int tid  = threadIdx.x;
    const int lane = tid & 63;
    const int wid  = tid >> 6;      // 0..15
    const int qg   = wid >> 1;      // 0..7 query group (64 q each)
    const int cg   = wid & 1;       // 0..1 code half (64 codes each)
    const int col  = lane & 15;     // MFMA col / A-row selector
    const int kh   = lane >> 4;     // k-chunk 0..3

    const int split = blockIdx.y;
    const int qblk  = blockIdx.x;
    const int cbase = split * CPS;

    // ---- A fragments: 4 subtiles x (hi,lo) of -2*z, resident ----
    bf16x8 ah[4], al[4];
    {
        const int qrow = qblk * QB + qg * 64;
#pragma unroll
        for (int s = 0; s < 4; ++s) {
            const float* zp = z + (size_t)(qrow + s*16 + col) * DIM + kh*8;
            float4 f0 = *(const float4*)zp;
            float4 f1 = *(const float4*)(zp + 4);
            float zf[8] = {f0.x,f0.y,f0.z,f0.w,f1.x,f1.y,f1.z,f1.w};
#pragma unroll
            for (int j = 0; j < 8; ++j) {
                float m2 = -2.0f * zf[j];
                unsigned short h = f2bf(m2);
                unsigned short l = f2bf(m2 - bf2f(h));
                ah[s][j] = (short)h;
                al[s][j] = (short)l;
            }
        }
    }

    // top-2 state per (subtile, reg) slot
    float d1s[4][4], d2s[4][4]; int i1s[4][4];
#pragma unroll
    for (int s = 0; s < 4; ++s)
#pragma unroll
        for (int r = 0; r < 4; ++r) { d1s[s][r] = INFINITY; d2s[s][r] = INFINITY; i1s[s][r] = 0; }

    // staging: each thread handles one 16B fp32 chunk (4 dims of one code)
    const int srow = tid >> 3;       // 0..127
    const int schk = tid & 7;        // dim group: 4*schk..+4
    float4 stg; float stgcn = 0.f;

    auto issue = [&](int s) {
        stg = *(const float4*)(cb + (size_t)(cbase + s*STAGE_C + srow) * DIM + schk*4);
        if (tid < STAGE_C) stgcn = cbn[cbase + s*STAGE_C + tid];
    };
    auto stage_write = [&](int buf) {
        float v[4] = {stg.x, stg.y, stg.z, stg.w};
        s16x4 hv, lv;
#pragma unroll
        for (int j = 0; j < 4; ++j) {
            unsigned short h = f2bf(v[j]);
            unsigned short l = f2bf(v[j] - bf2f(h));
            hv[j] = (short)h; lv[j] = (short)l;
        }
        short* base = (short*)(smem + buf * (STAGE_C * ROWB)) + srow * ROWS + schk * 4;
        *(s16x4*)base        = hv;
        *(s16x4*)(base + 32) = lv;
        if (tid < STAGE_C) {
            float* cnlb = (float*)(smem + 2*STAGE_C*ROWB + buf * (STAGE_C * 4));
            cnlb[tid] = stgcn;
        }
    };

    auto compute = [&](int buf, int sbase) {
        const short* csb = (const short*)(smem + buf * (STAGE_C * ROWB));
        const float* cnlb = (const float*)(smem + 2*STAGE_C*ROWB + buf * (STAGE_C * 4));
        const int idxb = sbase + cg*64 + col;
#pragma unroll
        for (int t = 0; t < 4; ++t) {
            const short* brow = csb + (cg*64 + t*16 + col) * ROWS + kh*8;
            bf16x8 bh = *(const bf16x8*)brow;
            bf16x8 bl = *(const bf16x8*)(brow + 32);
            float cnv = cnlb[cg*64 + t*16 + col];
            int idxv = idxb + t*16;
            f32x4 cacc = {cnv, cnv, cnv, cnv};   // fold ||c||^2 into C-in
#pragma unroll
            for (int s = 0; s < 4; ++s) {
                f32x4 acc = cacc;
                acc = __builtin_amdgcn_mfma_f32_16x16x32_bf16(ah[s], bh, acc, 0, 0, 0);
                acc = __builtin_amdgcn_mfma_f32_16x16x32_bf16(ah[s], bl, acc, 0, 0, 0);
                acc = __builtin_amdgcn_mfma_f32_16x16x32_bf16(al[s], bh, acc, 0, 0, 0);
#pragma unroll
                for (int r = 0; r < 4; ++r) {
                    float d   = acc[r];
                    float od1 = d1s[s][r];
                    d2s[s][r] = fminf(fmaxf(d, od1), d2s[s][r]);  // med3
                    d1s[s][r] = fminf(d, od1);
                    i1s[s][r] = (d < od1) ? idxv : i1s[s][r];
                }
            }
        }
    };

    // ---- main pipeline ----
    issue(0);
    stage_write(0);
    __syncthreads();
    int cur = 0;
    for (int s = 0; s < NSTAGE; ++s) {
        if (s + 1 < NSTAGE) issue(s + 1);
        compute(cur, cbase + s * STAGE_C);
        if (s + 1 < NSTAGE) stage_write(cur ^ 1);
        __syncthreads();
        cur ^= 1;
    }

    // ---- cross-lane top-2 merge over the 16 cols ----
#pragma unroll
    for (int m = 1; m < 16; m <<= 1) {
#pragma unroll
        for (int s = 0; s < 4; ++s)
#pragma unroll
            for (int r = 0; r < 4; ++r) {
                float od1 = __shfl_xor(d1s[s][r], m);
                float od2 = __shfl_xor(d2s[s][r], m);
                int   oi1 = __shfl_xor(i1s[s][r], m);
                float nd2 = fminf(fminf(d2s[s][r], od2), fmaxf(d1s[s][r], od1));
                i1s[s][r] = (od1 < d1s[s][r]) ? oi1 : i1s[s][r];
                d1s[s][r] = fminf(d1s[s][r], od1);
                d2s[s][r] = nd2;
            }
    }

    // ---- per-wave -> LDS, merge c-groups, write global partials ----
    if (col == 0) {
#pragma unroll
        for (int s = 0; s < 4; ++s)
#pragma unroll
            for (int r = 0; r < 4; ++r) {
                int o = wid * 64 + s * 16 + kh * 4 + r;
                redD1[o] = d1s[s][r];
                redD2[o] = d2s[s][r];
                redI1[o] = i1s[s][r];
            }
    }
    __syncthreads();
    if (tid < QB) {
        int qg2 = tid >> 6, lw = tid & 63;
        int a = (qg2 * 2) * 64 + lw, b = (qg2 * 2 + 1) * 64 + lw;
        float da1 = redD1[a], db1 = redD1[b];
        float da2 = redD2[a], db2 = redD2[b];
        int   ia  = redI1[a], ib  = redI1[b];
        float d2m = fminf(fminf(da2, db2), fmaxf(da1, db1));
        int   im  = (db1 < da1) ? ib : ia;
        float d1m = fminf(da1, db1);
        int q = qblk * QB + tid;
        pd1[(size_t)q * KSPLIT + split] = d1m;
        pd2[(size_t)q * KSPLIT + split] = d2m;
        pi1[(size_t)q * KSPLIT + split] = im;
    }
}

// merge k-splits (ascending split order + strict < == reference first-min tie-break)
__global__ __launch_bounds__(256) void combine_kernel(
    const float* __restrict__ pd1, const float* __restrict__ pd2,
    const int* __restrict__ pi1,
    int* __restrict__ fidx, int* __restrict__ list, int* __restrict__ cnt)
{
    int q = blockIdx.x * 256 + threadIdx.x;
    if (q >= NQ) return;
    float d1 = INFINITY, d2 = INFINITY;
    int i1 = 0;
#pragma unroll
    for (int s = 0; s < KSPLIT; ++s) {
        float da = pd1[(size_t)q * KSPLIT + s];
        float db = pd2[(size_t)q * KSPLIT + s];
        int   ia = pi1[(size_t)q * KSPLIT + s];
        if (da < d1) { d2 = fminf(d1, db); d1 = da; i1 = ia; }
        else         { d2 = fminf(d2, fminf(da, db)); }
    }
    fidx[q] = i1;
    if (d2 - d1 < MARGIN) {
        int p = atomicAdd(cnt, 1);
        list[p] = q;
    }
}

// exact double-precision re-rank of flagged (near-tie) queries
__global__ __launch_bounds__(256) void recheck_kernel(
    const float* __restrict__ z, const float* __restrict__ cb,
    const int* __restrict__ list, const int* __restrict__ cnt,
    int* __restrict__ fidx)
{
    __shared__ double sd[256];
    __shared__ int    si[256];
    int n = *cnt;
    int tid = threadIdx.x;
    for (int li = blockIdx.x; li < n; li += gridDim.x) {
        int q = list[li];
        const float* zq = z + (size_t)q * DIM;
        double zr[DIM];
#pragma unroll
        for (int d = 0; d < DIM; ++d) zr[d] = (double)zq[d];
        double bd = 1e300;
        int bi = 0;
        for (int k = tid; k < KCB; k += 256) {
            const float* c = cb + (size_t)k * DIM;
            double s = 0.0;
#pragma unroll
            for (int d = 0; d < DIM; ++d) {
                double df = zr[d] - (double)c[d];
                s = fma(df, df, s);
            }
            if (s < bd) { bd = s; bi = k; }   // ascending k -> first-min kept
        }
        sd[tid] = bd; si[tid] = bi;
        __syncthreads();
        for (int off = 128; off > 0; off >>= 1) {
            if (tid < off) {
                double od = sd[tid + off]; int oi = si[tid + off];
                if (od < sd[tid] || (od == sd[tid] && oi < si[tid])) { sd[tid] = od; si[tid] = oi; }
            }
            __syncthreads();
        }
        if (tid == 0) fidx[q] = si[0];
        __syncthreads();
    }
}

// noisy quantization + idx output + histogram
__global__ __launch_bounds__(256) void rows_kernel(
    const float* __restrict__ z, const float* __restrict__ noise,
    const float* __restrict__ cb, const int* __restrict__ fidx,
    float* __restrict__ out, float* __restrict__ counts)
{
    int q = blockIdx.x * 256 + threadIdx.x;
    if (q >= NQ) return;
    int idx = fidx[q];
    const float4* zp  = (const float4*)(z + (size_t)q * DIM);
    const float4* np_ = (const float4*)(noise + (size_t)q * DIM);
    const float4* cp  = (const float4*)(cb + (size_t)idx * DIM);
    float zr[DIM], nr[DIM], cr[DIM];
#pragma unroll
    for (int c = 0; c < 8; ++c) {
        float4 a = zp[c], b = np_[c], d = cp[c];
        zr[4*c]=a.x; zr[4*c+1]=a.y; zr[4*c+2]=a.z; zr[4*c+3]=a.w;
        nr[4*c]=b.x; nr[4*c+1]=b.y; nr[4*c+2]=b.z; nr[4*c+3]=b.w;
        cr[4*c]=d.x; cr[4*c+1]=d.y; cr[4*c+2]=d.z; cr[4*c+3]=d.w;
    }
    const float noise_std = 0.0316227766016838f;  // sqrt(0.001)
    float ds = 0.f, dn = 0.f;
    float dd[DIM];
#pragma unroll
    for (int d = 0; d < DIM; ++d) {
        float df = cr[d] - zr[d];
        ds = fmaf(df, df, ds);
        float v = fmaf(noise_std, nr[d], df);
        dd[d] = v;
        dn = fmaf(v, v, dn);
    }
    float diff_norm = fmaxf(sqrtf(ds), 1e-8f);
    float dir_norm  = fmaxf(sqrtf(dn), 1e-8f);
    float scale = diff_norm / dir_norm;
    float4* op = (float4*)(out + (size_t)q * DIM);
#pragma unroll
    for (int c = 0; c < 8; ++c) {
        op[c] = make_float4(fmaf(scale, dd[4*c+0], zr[4*c+0]),
                            fmaf(scale, dd[4*c+1], zr[4*c+1]),
                            fmaf(scale, dd[4*c+2], zr[4*c+2]),
                            fmaf(scale, dd[4*c+3], zr[4*c+3]));
    }
    out[NZQ + 2 + q] = (float)idx;
    atomicAdd(&counts[idx], 1.0f);
}

// entropy + usage partial reduction
__global__ __launch_bounds__(256) void stats_kernel(
    const float* __restrict__ counts, float* __restrict__ stats)
{
    int i = blockIdx.x * 256 + threadIdx.x;
    float c = counts[i];
    float p = c * (1.0f / 32768.0f);   // total == NQ always
    float s = (c > 0.f) ? p * logf(p + 1e-10f) : 0.f;
    float u = (c > 0.f) ? 1.f : 0.f;
#pragma unroll
    for (int off = 32; off > 0; off >>= 1) {
        s += __shfl_down(s, off);
        u += __shfl_down(u, off);
    }
    __shared__ float ss[4], su[4];
    int wid = threadIdx.x >> 6, lane = threadIdx.x & 63;
    if (lane == 0) { ss[wid] = s; su[wid] = u; }
    __syncthreads();
    if (threadIdx.x == 0) {
        atomicAdd(&stats[0], ss[0] + ss[1] + ss[2] + ss[3]);
        atomicAdd(&stats[1], su[0] + su[1] + su[2] + su[3]);
    }
}

__global__ void epilogue_kernel(const float* __restrict__ stats, float* __restrict__ out) {
    if (threadIdx.x == 0) {
        out[NZQ]     = expf(-stats[0]);
        out[NZQ + 1] = stats[1] * (1.0f / 65536.0f);
    }
}

extern "C" void kernel_launch(void* const* d_in, const int* in_sizes, int n_in,
                              void* d_out, int out_size, void* d_ws, size_t ws_size,
                              hipStream_t stream)
{
    const float* z        = (const float*)d_in[0];
    const float* codebook = (const float*)d_in[1];
    const float* W        = (const float*)d_in[2];
    const float* bias     = (const float*)d_in[3];
    const float* noise    = (const float*)d_in[4];
    float* out = (float*)d_out;
    float* ws  = (float*)d_ws;

    float* cb     = ws + OFF_CB;
    float* cbn    = ws + OFF_CBN;
    float* pd1    = ws + OFF_PD1;
    float* pd2    = ws + OFF_PD2;
    int*   pi1    = (int*)(ws + OFF_PI1);
    int*   fidx   = (int*)(ws + OFF_FIDX);
    int*   list   = (int*)(ws + OFF_LIST);
    float* counts = ws + OFF_COUNTS;
    int*   cnt    = (int*)(ws + OFF_CNT);
    float* stats  = ws + OFF_STATS;

    // zero counts + cnt + stats (contiguous K+3 floats/ints)
    zero_kernel<<<(KCB + 3 + 255) / 256, 256, 0, stream>>>(counts, KCB + 3);
    project_kernel<<<KCB / 256, 256, 0, stream>>>(codebook, W, bias, cb, cbn);
    dim3 sg(NQB, KSPLIT);
    search_kernel<<<sg, 1024, 0, stream>>>(z, cb, cbn, pd1, pd2, pi1);
    combine_kernel<<<NQ / 256, 256, 0, stream>>>(pd1, pd2, pi1, fidx, list, cnt);
    recheck_kernel<<<512, 256, 0, stream>>>(z, cb, list, cnt, fidx);
    rows_kernel<<<NQ / 256, 256, 0, stream>>>(z, noise, cb, fidx, out, counts);
    stats_kernel<<<KCB / 256, 256, 0, stream>>>(counts, stats);
    epilogue_kernel<<<1, 64, 0, stream>>>(stats, out);
}

// Round 9
// 1067.251 us; speedup vs baseline: 2.2958x; 2.2958x over previous
//
#include <hip/hip_runtime.h>
#include <math.h>

#define KCB 65536
#define DIM 32
#define NQ  32768            // B*T = 8*4096
#define KSPLIT 8
#define CPS (KCB / KSPLIT)   // 8192 codes per split
#define STAGE_C 128          // codes staged in LDS per step
#define NSTAGE (CPS / STAGE_C) // 64
#define QB  256              // queries per block (4 waves x 64 q)
#define NQB (NQ / QB)        // 128 query blocks
#define ROWB 144             // LDS bytes per code row: 64 hi + 64 lo + 16 pad
#define ROWS (ROWB/2)        // 72 shorts
#define NZQ (NQ * DIM)       // 1048576 z_q elements
#define MARGIN 1e-3f

// ---- workspace layout (units of 4 bytes) ----
#define OFF_CB      ((size_t)0)                       // K*D floats (projected codebook)
#define OFF_CBN     (OFF_CB + (size_t)KCB * DIM)      // K floats (||cb||^2)
#define OFF_PD1     (OFF_CBN + KCB)                   // NQ*KSPLIT floats
#define OFF_PD2     (OFF_PD1 + (size_t)NQ * KSPLIT)   // NQ*KSPLIT floats
#define OFF_PI1     (OFF_PD2 + (size_t)NQ * KSPLIT)   // NQ*KSPLIT ints
#define OFF_FIDX    (OFF_PI1 + (size_t)NQ * KSPLIT)   // NQ ints
#define OFF_LIST    (OFF_FIDX + NQ)                   // NQ ints
#define OFF_COUNTS  (OFF_LIST + NQ)                   // K floats
#define OFF_CNT     (OFF_COUNTS + KCB)                // 1 int
#define OFF_STATS   (OFF_CNT + 1)                     // 2 floats (S, U)

typedef __attribute__((ext_vector_type(8))) short bf16x8;
typedef __attribute__((ext_vector_type(4))) short s16x4;
typedef __attribute__((ext_vector_type(4))) float f32x4;

__device__ __forceinline__ unsigned short f2bf(float f) {
    unsigned int u = __builtin_bit_cast(unsigned int, f);
    unsigned int r = (u + 0x7FFFu + ((u >> 16) & 1u)) >> 16;  // RNE
    return (unsigned short)r;
}
__device__ __forceinline__ float bf2f(unsigned short h) {
    unsigned int u = ((unsigned int)h) << 16;
    return __builtin_bit_cast(float, u);
}

__global__ __launch_bounds__(256) void zero_kernel(float* __restrict__ p, int n) {
    int i = blockIdx.x * 256 + threadIdx.x;
    if (i < n) p[i] = 0.0f;
}

// cb = codebook @ W + bias  (double accumulate -> round), plus exact row norms
__global__ __launch_bounds__(256) void project_kernel(
    const float* __restrict__ codebook, const float* __restrict__ W,
    const float* __restrict__ bias, float* __restrict__ cb, float* __restrict__ cbn)
{
    __shared__ float Ws[DIM * DIM];
    __shared__ float bs[DIM];
    int tid = threadIdx.x;
#pragma unroll
    for (int r = 0; r < 4; ++r) Ws[tid + 256 * r] = W[tid + 256 * r];
    if (tid < DIM) bs[tid] = bias[tid];
    __syncthreads();
    int k = blockIdx.x * 256 + tid;
    float row[DIM];
    const float4* src = (const float4*)(codebook + (size_t)k * DIM);
#pragma unroll
    for (int c = 0; c < 8; ++c) {
        float4 v = src[c];
        row[4*c] = v.x; row[4*c+1] = v.y; row[4*c+2] = v.z; row[4*c+3] = v.w;
    }
    float out[DIM];
    double nrm = 0.0;
#pragma unroll
    for (int d = 0; d < DIM; ++d) {
        double acc = 0.0;
#pragma unroll
        for (int j = 0; j < DIM; ++j) acc += (double)row[j] * (double)Ws[j * DIM + d];
        acc += (double)bs[d];
        float o = (float)acc;
        out[d] = o;
        nrm += (double)o * (double)o;
    }
    float4* dst = (float4*)(cb + (size_t)k * DIM);
#pragma unroll
    for (int c = 0; c < 8; ++c)
        dst[c] = make_float4(out[4*c], out[4*c+1], out[4*c+2], out[4*c+3]);
    cbn[k] = (float)nrm;
}

// MFMA-based top-2 NN search on partial distance p = ||c||^2 - 2 z.c
// (zn omitted: constant per query, cancels in argmin and in d2-d1 margin).
// Block: 256 thr = 4 waves = 4 q-groups x 64 queries; each wave computes all
// 128 staged codes (8 c-subtiles). Grid: (NQ/256, KSPLIT) = 1024 blocks.
// 256-thr blocks: hipcc allocates VGPRs freely (1024-thr blocks were pinned
// at 64 VGPR -> ~45-reg spill -> 10 GB scratch traffic, the R5/R7 bottleneck).
__global__ __launch_bounds__(256) void search_kernel(
    const float* __restrict__ z, const float* __restrict__ cb,
    const float* __restrict__ cbn,
    float* __restrict__ pd1, float* __restrict__ pd2, int* __restrict__ pi1)
{
    __shared__ __align__(16) unsigned char smem[2*STAGE_C*ROWB + 2*STAGE_C*4];

    const int tid  = threadIdx.x;
    const int lane = tid & 63;
    const int qg   = tid >> 6;      // 0..3 query group (64 q each)
    const int col  = lane & 15;     // MFMA col (code index within subtile)
    const int kh   = lane >> 4;     // k-chunk 0..3

    const int split = blockIdx.y;
    const int qblk  = blockIdx.x;
    const int cbase = split * CPS;

    // ---- A fragments: 4 subtiles x (hi,lo) of -2*z, resident ----
    bf16x8 ah[4], al[4];
    {
        const int qrow = qblk * QB + qg * 64;
#pragma unroll
        for (int s = 0; s < 4; ++s) {
            const float* zp = z + (size_t)(qrow + s*16 + col) * DIM + kh*8;
            float4 f0 = *(const float4*)zp;
            float4 f1 = *(const float4*)(zp + 4);
            float zf[8] = {f0.x,f0.y,f0.z,f0.w,f1.x,f1.y,f1.z,f1.w};
#pragma unroll
            for (int j = 0; j < 8; ++j) {
                float m2 = -2.0f * zf[j];
                unsigned short h = f2bf(m2);
                unsigned short l = f2bf(m2 - bf2f(h));
                ah[s][j] = (short)h;
                al[s][j] = (short)l;
            }
        }
    }

    // top-2 state per (q-subtile s, acc reg r) slot
    float d1s[4][4], d2s[4][4]; int i1s[4][4];
#pragma unroll
    for (int s = 0; s < 4; ++s)
#pragma unroll
        for (int r = 0; r < 4; ++r) { d1s[s][r] = INFINITY; d2s[s][r] = INFINITY; i1s[s][r] = 0; }

    // staging: 128 rows x 8 chunks = 1024 float4; 4 chunks per thread
    float4 stg[4]; float stgcn = 0.f;

    auto issue = [&](int st) {
#pragma unroll
        for (int i = 0; i < 4; ++i) {
            int cid = tid + 256 * i;
            int r = cid >> 3, c = cid & 7;
            stg[i] = *(const float4*)(cb + (size_t)(cbase + st*STAGE_C + r) * DIM + c*4);
        }
        if (tid < STAGE_C) stgcn = cbn[cbase + st*STAGE_C + tid];
    };
    auto stage_write = [&](int buf) {
#pragma unroll
        for (int i = 0; i < 4; ++i) {
            int cid = tid + 256 * i;
            int rr = cid >> 3, c = cid & 7;
            float v[4] = {stg[i].x, stg[i].y, stg[i].z, stg[i].w};
            s16x4 hv, lv;
#pragma unroll
            for (int j = 0; j < 4; ++j) {
                unsigned short h = f2bf(v[j]);
                unsigned short l = f2bf(v[j] - bf2f(h));
                hv[j] = (short)h; lv[j] = (short)l;
            }
            short* base = (short*)(smem + buf * (STAGE_C * ROWB)) + rr * ROWS + c * 4;
            *(s16x4*)base        = hv;
            *(s16x4*)(base + 32) = lv;
        }
        if (tid < STAGE_C) {
            float* cnlb = (float*)(smem + 2*STAGE_C*ROWB + buf * (STAGE_C * 4));
            cnlb[tid] = stgcn;
        }
    };

    auto compute = [&](int buf, int sbase) {
        const short* csb  = (const short*)(smem + buf * (STAGE_C * ROWB));
        const float* cnlb = (const float*)(smem + 2*STAGE_C*ROWB + buf * (STAGE_C * 4));
#pragma unroll
        for (int t = 0; t < 8; ++t) {
            const short* brow = csb + (t*16 + col) * ROWS + kh*8;
            bf16x8 bh = *(const bf16x8*)brow;
            bf16x8 bl = *(const bf16x8*)(brow + 32);
            float cnv = cnlb[t*16 + col];
            int idxv = sbase + t*16 + col;
            f32x4 cacc = {cnv, cnv, cnv, cnv};   // fold ||c||^2 into C-in
#pragma unroll
            for (int s = 0; s < 4; ++s) {
                f32x4 acc = cacc;
                acc = __builtin_amdgcn_mfma_f32_16x16x32_bf16(ah[s], bh, acc, 0, 0, 0);
                acc = __builtin_amdgcn_mfma_f32_16x16x32_bf16(ah[s], bl, acc, 0, 0, 0);
                acc = __builtin_amdgcn_mfma_f32_16x16x32_bf16(al[s], bh, acc, 0, 0, 0);
#pragma unroll
                for (int r = 0; r < 4; ++r) {
                    float d   = acc[r];
                    float od1 = d1s[s][r];
                    d2s[s][r] = fminf(fmaxf(d, od1), d2s[s][r]);  // -> v_med3
                    d1s[s][r] = fminf(d, od1);
                    i1s[s][r] = (d < od1) ? idxv : i1s[s][r];
                }
            }
        }
    };

    // ---- main pipeline ----
    issue(0);
    stage_write(0);
    __syncthreads();
    int cur = 0;
    for (int s = 0; s < NSTAGE; ++s) {
        if (s + 1 < NSTAGE) issue(s + 1);
        compute(cur, cbase + s * STAGE_C);
        if (s + 1 < NSTAGE) stage_write(cur ^ 1);
        __syncthreads();
        cur ^= 1;
    }

    // ---- cross-lane top-2 merge over the 16 cols ----
#pragma unroll
    for (int m = 1; m < 16; m <<= 1) {
#pragma unroll
        for (int s = 0; s < 4; ++s)
#pragma unroll
            for (int r = 0; r < 4; ++r) {
                float od1 = __shfl_xor(d1s[s][r], m);
                float od2 = __shfl_xor(d2s[s][r], m);
                int   oi1 = __shfl_xor(i1s[s][r], m);
                float nd2 = fminf(fminf(d2s[s][r], od2), fmaxf(d1s[s][r], od1));
                i1s[s][r] = (od1 < d1s[s][r]) ? oi1 : i1s[s][r];
                d1s[s][r] = fminf(d1s[s][r], od1);
                d2s[s][r] = nd2;
            }
    }

    // ---- col==0 lanes hold the merged top-2 for 16 queries each ----
    if (col == 0) {
        const int qb = qblk * QB + qg * 64;
#pragma unroll
        for (int s = 0; s < 4; ++s)
#pragma unroll
            for (int r = 0; r < 4; ++r) {
                int q = qb + s*16 + kh*4 + r;
                size_t o = (size_t)q * KSPLIT + split;
                pd1[o] = d1s[s][r];
                pd2[o] = d2s[s][r];
                pi1[o] = i1s[s][r];
            }
    }
}

// merge k-splits (ascending split order + strict < == reference first-min tie-break)
__global__ __launch_bounds__(256) void combine_kernel(
    const float* __restrict__ pd1, const float* __restrict__ pd2,
    const int* __restrict__ pi1,
    int* __restrict__ fidx, int* __restrict__ list, int* __restrict__ cnt)
{
    int q = blockIdx.x * 256 + threadIdx.x;
    if (q >= NQ) return;
    float d1 = INFINITY, d2 = INFINITY;
    int i1 = 0;
#pragma unroll
    for (int s = 0; s < KSPLIT; ++s) {
        float da = pd1[(size_t)q * KSPLIT + s];
        float db = pd2[(size_t)q * KSPLIT + s];
        int   ia = pi1[(size_t)q * KSPLIT + s];
        if (da < d1) { d2 = fminf(d1, db); d1 = da; i1 = ia; }
        else         { d2 = fminf(d2, fminf(da, db)); }
    }
    fidx[q] = i1;
    if (d2 - d1 < MARGIN) {
        int p = atomicAdd(cnt, 1);
        list[p] = q;
    }
}

// exact double-precision re-rank of flagged (near-tie) queries
__global__ __launch_bounds__(256) void recheck_kernel(
    const float* __restrict__ z, const float* __restrict__ cb,
    const int* __restrict__ list, const int* __restrict__ cnt,
    int* __restrict__ fidx)
{
    __shared__ double sd[256];
    __shared__ int    si[256];
    int n = *cnt;
    int tid = threadIdx.x;
    for (int li = blockIdx.x; li < n; li += gridDim.x) {
        int q = list[li];
        const float* zq = z + (size_t)q * DIM;
        double zr[DIM];
#pragma unroll
        for (int d = 0; d < DIM; ++d) zr[d] = (double)zq[d];
        double bd = 1e300;
        int bi = 0;
        for (int k = tid; k < KCB; k += 256) {
            const float* c = cb + (size_t)k * DIM;
            double s = 0.0;
#pragma unroll
            for (int d = 0; d < DIM; ++d) {
                double df = zr[d] - (double)c[d];
                s = fma(df, df, s);
            }
            if (s < bd) { bd = s; bi = k; }   // ascending k -> first-min kept
        }
        sd[tid] = bd; si[tid] = bi;
        __syncthreads();
        for (int off = 128; off > 0; off >>= 1) {
            if (tid < off) {
                double od = sd[tid + off]; int oi = si[tid + off];
                if (od < sd[tid] || (od == sd[tid] && oi < si[tid])) { sd[tid] = od; si[tid] = oi; }
            }
            __syncthreads();
        }
        if (tid == 0) fidx[q] = si[0];
        __syncthreads();
    }
}

// noisy quantization + idx output + histogram
__global__ __launch_bounds__(256) void rows_kernel(
    const float* __restrict__ z, const float* __restrict__ noise,
    const float* __restrict__ cb, const int* __restrict__ fidx,
    float* __restrict__ out, float* __restrict__ counts)
{
    int q = blockIdx.x * 256 + threadIdx.x;
    if (q >= NQ) return;
    int idx = fidx[q];
    const float4* zp  = (const float4*)(z + (size_t)q * DIM);
    const float4* np_ = (const float4*)(noise + (size_t)q * DIM);
    const float4* cp  = (const float4*)(cb + (size_t)idx * DIM);
    float zr[DIM], nr[DIM], cr[DIM];
#pragma unroll
    for (int c = 0; c < 8; ++c) {
        float4 a = zp[c], b = np_[c], d = cp[c];
        zr[4*c]=a.x; zr[4*c+1]=a.y; zr[4*c+2]=a.z; zr[4*c+3]=a.w;
        nr[4*c]=b.x; nr[4*c+1]=b.y; nr[4*c+2]=b.z; nr[4*c+3]=b.w;
        cr[4*c]=d.x; cr[4*c+1]=d.y; cr[4*c+2]=d.z; cr[4*c+3]=d.w;
    }
    const float noise_std = 0.0316227766016838f;  // sqrt(0.001)
    float ds = 0.f, dn = 0.f;
    float dd[DIM];
#pragma unroll
    for (int d = 0; d < DIM; ++d) {
        float df = cr[d] - zr[d];
        ds = fmaf(df, df, ds);
        float v = fmaf(noise_std, nr[d], df);
        dd[d] = v;
        dn = fmaf(v, v, dn);
    }
    float diff_norm = fmaxf(sqrtf(ds), 1e-8f);
    float dir_norm  = fmaxf(sqrtf(dn), 1e-8f);
    float scale = diff_norm / dir_norm;
    float4* op = (float4*)(out + (size_t)q * DIM);
#pragma unroll
    for (int c = 0; c < 8; ++c) {
        op[c] = make_float4(fmaf(scale, dd[4*c+0], zr[4*c+0]),
                            fmaf(scale, dd[4*c+1], zr[4*c+1]),
                            fmaf(scale, dd[4*c+2], zr[4*c+2]),
                            fmaf(scale, dd[4*c+3], zr[4*c+3]));
    }
    out[NZQ + 2 + q] = (float)idx;
    atomicAdd(&counts[idx], 1.0f);
}

// entropy + usage partial reduction
__global__ __launch_bounds__(256) void stats_kernel(
    const float* __restrict__ counts, float* __restrict__ stats)
{
    int i = blockIdx.x * 256 + threadIdx.x;
    float c = counts[i];
    float p = c * (1.0f / 32768.0f);   // total == NQ always
    float s = (c > 0.f) ? p * logf(p + 1e-10f) : 0.f;
    float u = (c > 0.f) ? 1.f : 0.f;
#pragma unroll
    for (int off = 32; off > 0; off >>= 1) {
        s += __shfl_down(s, off);
        u += __shfl_down(u, off);
    }
    __shared__ float ss[4], su[4];
    int wid = threadIdx.x >> 6, lane = threadIdx.x & 63;
    if (lane == 0) { ss[wid] = s; su[wid] = u; }
    __syncthreads();
    if (threadIdx.x == 0) {
        atomicAdd(&stats[0], ss[0] + ss[1] + ss[2] + ss[3]);
        atomicAdd(&stats[1], su[0] + su[1] + su[2] + su[3]);
    }
}

__global__ void epilogue_kernel(const float* __restrict__ stats, float* __restrict__ out) {
    if (threadIdx.x == 0) {
        out[NZQ]     = expf(-stats[0]);
        out[NZQ + 1] = stats[1] * (1.0f / 65536.0f);
    }
}

extern "C" void kernel_launch(void* const* d_in, const int* in_sizes, int n_in,
                              void* d_out, int out_size, void* d_ws, size_t ws_size,
                              hipStream_t stream)
{
    const float* z        = (const float*)d_in[0];
    const float* codebook = (const float*)d_in[1];
    const float* W        = (const float*)d_in[2];
    const float* bias     = (const float*)d_in[3];
    const float* noise    = (const float*)d_in[4];
    float* out = (float*)d_out;
    float* ws  = (float*)d_ws;

    float* cb     = ws + OFF_CB;
    float* cbn    = ws + OFF_CBN;
    float* pd1    = ws + OFF_PD1;
    float* pd2    = ws + OFF_PD2;
    int*   pi1    = (int*)(ws + OFF_PI1);
    int*   fidx   = (int*)(ws + OFF_FIDX);
    int*   list   = (int*)(ws + OFF_LIST);
    float* counts = ws + OFF_COUNTS;
    int*   cnt    = (int*)(ws + OFF_CNT);
    float* stats  = ws + OFF_STATS;

    // zero counts + cnt + stats (contiguous K+3 floats/ints)
    zero_kernel<<<(KCB + 3 + 255) / 256, 256, 0, stream>>>(counts, KCB + 3);
    project_kernel<<<KCB / 256, 256, 0, stream>>>(codebook, W, bias, cb, cbn);
    dim3 sg(NQB, KSPLIT);
    search_kernel<<<sg, 256, 0, stream>>>(z, cb, cbn, pd1, pd2, pi1);
    combine_kernel<<<NQ / 256, 256, 0, stream>>>(pd1, pd2, pi1, fidx, list, cnt);
    recheck_kernel<<<512, 256, 0, stream>>>(z, cb, list, cnt, fidx);
    rows_kernel<<<NQ / 256, 256, 0, stream>>>(z, noise, cb, fidx, out, counts);
    stats_kernel<<<KCB / 256, 256, 0, stream>>>(counts, stats);
    epilogue_kernel<<<1, 64, 0, stream>>>(stats, out);
}